// Round 8
// baseline (143.026 us; speedup 1.0000x reference)
//
#include <hip/hip_runtime.h>
#include <hip/hip_bf16.h>

#define LNUM 16
#define DDIM 1024
#define MTOK 4096   // B*T = 2*2048

using bf16x8 = __attribute__((ext_vector_type(8))) short;
using s4v    = __attribute__((ext_vector_type(4))) short;
using f32x4  = __attribute__((ext_vector_type(4))) float;

__device__ inline short f2b(float f) {
  __hip_bfloat16 h = __float2bfloat16(f);
  union { __hip_bfloat16 h; short s; } u; u.h = h; return u.s;
}
__device__ inline float b2f(short s) {
  unsigned int u = ((unsigned int)(unsigned short)s) << 16;
  float f; __builtin_memcpy(&f, &u, 4); return f;
}
__device__ inline float bitsf(unsigned int u) {
  float f; __builtin_memcpy(&f, &u, 4); return f;
}

// ---------------------------------------------------------------------------
// Merged prologue kernel (R6-identical).
// ---------------------------------------------------------------------------
__global__ __launch_bounds__(256)
void pre_k(const float* __restrict__ wk, const float* __restrict__ wq,
           short* __restrict__ Wt,
           const float* __restrict__ xlast, short* __restrict__ xb)
{
  __shared__ short As[2][64 * 64];
  __shared__ short Bs[2][64 * 64];
  const int tid = threadIdx.x;

  if (blockIdx.x >= 256) {
    const size_t i = ((size_t)(blockIdx.x - 256) * 256 + tid) * 8;
    const float4 a = *reinterpret_cast<const float4*>(xlast + i);
    const float4 b = *reinterpret_cast<const float4*>(xlast + i + 4);
    bf16x8 v = { f2b(a.x), f2b(a.y), f2b(a.z), f2b(a.w),
                 f2b(b.x), f2b(b.y), f2b(b.z), f2b(b.w) };
    *reinterpret_cast<bf16x8*>(xb + i) = v;
    return;
  }

  const int lane = tid & 63;
  const int wave = tid >> 6;
  const int m0 = (blockIdx.x & 15) * 64;
  const int n0 = (blockIdx.x >> 4) * 64;
  const int wm = (wave >> 1) * 32;
  const int wn = (wave & 1) * 32;

  f32x4 acc[2][2] = {};
  const int col = tid & 63;
  const int kg  = tid >> 6;

  float ar[16], br[16];
  auto load = [&](int k0) {
    #pragma unroll
    for (int j = 0; j < 16; ++j) {
      const size_t k = (size_t)(k0 + kg * 16 + j);
      ar[j] = wk[k * 1024 + m0 + col];
      br[j] = wq[k * 1024 + n0 + col];
    }
  };
  auto store_lds = [&](int buf) {
    bf16x8 va0 = { f2b(ar[0]), f2b(ar[1]), f2b(ar[2]), f2b(ar[3]),
                   f2b(ar[4]), f2b(ar[5]), f2b(ar[6]), f2b(ar[7]) };
    bf16x8 va1 = { f2b(ar[8]), f2b(ar[9]), f2b(ar[10]), f2b(ar[11]),
                   f2b(ar[12]), f2b(ar[13]), f2b(ar[14]), f2b(ar[15]) };
    bf16x8 vb0 = { f2b(br[0]), f2b(br[1]), f2b(br[2]), f2b(br[3]),
                   f2b(br[4]), f2b(br[5]), f2b(br[6]), f2b(br[7]) };
    bf16x8 vb1 = { f2b(br[8]), f2b(br[9]), f2b(br[10]), f2b(br[11]),
                   f2b(br[12]), f2b(br[13]), f2b(br[14]), f2b(br[15]) };
    const int sw = (col & 7) << 4;
    const int b0 = (col * 128 + kg * 32) ^ sw;
    const int b1 = (col * 128 + kg * 32 + 16) ^ sw;
    char* pa = (char*)&As[buf][0];
    char* pb = (char*)&Bs[buf][0];
    *reinterpret_cast<bf16x8*>(pa + b0) = va0;
    *reinterpret_cast<bf16x8*>(pa + b1) = va1;
    *reinterpret_cast<bf16x8*>(pb + b0) = vb0;
    *reinterpret_cast<bf16x8*>(pb + b1) = vb1;
  };

  const int rl = lane & 15;
  const int hi = lane >> 4;
  auto compute = [&](int buf) {
    #pragma unroll
    for (int kk = 0; kk < 2; ++kk) {
      bf16x8 af[2], bfv[2];
      #pragma unroll
      for (int f = 0; f < 2; ++f) {
        const int row = wm + f * 16 + rl;
        af[f] = *reinterpret_cast<const bf16x8*>(
            (const char*)&As[buf][0] + ((row * 128 + kk * 64 + hi * 16) ^ ((row & 7) << 4)));
      }
      #pragma unroll
      for (int g = 0; g < 2; ++g) {
        const int row = wn + g * 16 + rl;
        bfv[g] = *reinterpret_cast<const bf16x8*>(
            (const char*)&Bs[buf][0] + ((row * 128 + kk * 64 + hi * 16) ^ ((row & 7) << 4)));
      }
      #pragma unroll
      for (int f = 0; f < 2; ++f)
        #pragma unroll
        for (int g = 0; g < 2; ++g)
          acc[f][g] = __builtin_amdgcn_mfma_f32_16x16x32_bf16(af[f], bfv[g], acc[f][g], 0, 0, 0);
    }
  };

  load(0);
  for (int t = 0; t < 16; ++t) {
    store_lds(t & 1);
    if (t < 15) load((t + 1) * 64);
    __syncthreads();
    compute(t & 1);
  }

  const int cl = lane & 15;
  const int rb = (lane >> 4) * 4;
  #pragma unroll
  for (int f = 0; f < 2; ++f)
    #pragma unroll
    for (int g = 0; g < 2; ++g) {
      size_t c = (size_t)(n0 + wn + g * 16 + cl);
      #pragma unroll
      for (int r = 0; r < 4; ++r) {
        size_t rr = (size_t)(m0 + wm + f * 16 + rb + r);
        Wt[rr * 1024 + c] = f2b(acc[f][g][r]);
      }
    }
}

// ---------------------------------------------------------------------------
// qk = xb @ Wt^T (R6-identical: 64x64 tiles, 1024 blocks, glds+swizzle dbuf)
// ---------------------------------------------------------------------------
__global__ __launch_bounds__(256)
void qk_gemm_k(const short* __restrict__ A, const short* __restrict__ B,
               short* __restrict__ C)
{
  __shared__ short As[2][64 * 64];
  __shared__ short Bs[2][64 * 64];
  const int tid  = threadIdx.x;
  const int lane = tid & 63;
  const int wave = tid >> 6;
  const int m0 = blockIdx.x * 64;
  const int n0 = blockIdx.y * 64;
  const int wm = (wave >> 1) * 32;
  const int wn = (wave & 1) * 32;

  f32x4 acc[2][2] = {};

  const int srow = lane >> 3;
  const int swz  = ((lane & 7) * 16) ^ (srow << 4);

  auto stage = [&](int buf, int k0) {
    #pragma unroll
    for (int c = 0; c < 2; ++c) {
      const int ch = wave * 2 + c;
      const int r  = ch * 8 + srow;
      const short* ga = A + (size_t)(m0 + r) * 1024 + k0 + (swz >> 1);
      __builtin_amdgcn_global_load_lds(
          (const __attribute__((address_space(1))) void*)ga,
          (__attribute__((address_space(3))) void*)&As[buf][ch * 512], 16, 0, 0);
    }
    #pragma unroll
    for (int c = 0; c < 2; ++c) {
      const int ch = wave * 2 + c;
      const int r  = ch * 8 + srow;
      const short* gb = B + (size_t)(n0 + r) * 1024 + k0 + (swz >> 1);
      __builtin_amdgcn_global_load_lds(
          (const __attribute__((address_space(1))) void*)gb,
          (__attribute__((address_space(3))) void*)&Bs[buf][ch * 512], 16, 0, 0);
    }
  };

  const int rl = lane & 15;
  const int hi = lane >> 4;
  auto compute = [&](int buf) {
    #pragma unroll
    for (int kk = 0; kk < 2; ++kk) {
      bf16x8 af[2], bfv[2];
      #pragma unroll
      for (int i = 0; i < 2; ++i) {
        const int row = wm + i * 16 + rl;
        af[i] = *reinterpret_cast<const bf16x8*>(
            (const char*)&As[buf][0] + ((row * 128 + kk * 64 + hi * 16) ^ ((row & 7) << 4)));
      }
      #pragma unroll
      for (int g = 0; g < 2; ++g) {
        const int row = wn + g * 16 + rl;
        bfv[g] = *reinterpret_cast<const bf16x8*>(
            (const char*)&Bs[buf][0] + ((row * 128 + kk * 64 + hi * 16) ^ ((row & 7) << 4)));
      }
      #pragma unroll
      for (int i = 0; i < 2; ++i)
        #pragma unroll
        for (int g = 0; g < 2; ++g)
          acc[i][g] = __builtin_amdgcn_mfma_f32_16x16x32_bf16(af[i], bfv[g], acc[i][g], 0, 0, 0);
    }
  };

  stage(0, 0);
  __syncthreads();
  int buf = 0;
  for (int t = 0; t < 16; ++t) {
    if (t < 15) stage(buf ^ 1, (t + 1) * 64);
    compute(buf);
    __syncthreads();
    buf ^= 1;
  }

  const int cl = lane & 15;
  const int rb = (lane >> 4) * 4;
  #pragma unroll
  for (int i = 0; i < 2; ++i)
    #pragma unroll
    for (int g = 0; g < 2; ++g) {
      size_t c = (size_t)(n0 + wn + g * 16 + cl);
      #pragma unroll
      for (int r = 0; r < 4; ++r) {
        size_t rr = (size_t)(m0 + wm + i * 16 + rb + r);
        C[rr * 1024 + c] = f2b(acc[i][g][r]);
      }
    }
}

// ---------------------------------------------------------------------------
// Fused pass (R6-identical). Launched TWICE this round (scratch, then real)
// as a timing probe: dur_R7 - dur_R6 = T_fused.
// ---------------------------------------------------------------------------
__global__ __launch_bounds__(256)
void fused_k(const float* __restrict__ layers, const short* __restrict__ qk,
             const float* __restrict__ scales, const float* __restrict__ temp,
             const float* __restrict__ lnw, const float* __restrict__ lnb,
             float* __restrict__ out)
{
  const int p    = blockIdx.x;
  const int tid  = threadIdx.x;
  const int lane = tid & 63;
  const int wave = tid >> 6;

  __shared__ float s_scales[16];
  __shared__ float s_red[4][16];
  __shared__ float s_scores[16];
  __shared__ float s_mv[4][2];

  if (tid < 16) s_scales[tid] = scales[tid];

  const size_t base = (size_t)p * DDIM + (size_t)tid * 4;
  s4v qv = *reinterpret_cast<const s4v*>(qk + base);
  const float q0 = b2f(qv.x), q1 = b2f(qv.y), q2 = b2f(qv.z), q3 = b2f(qv.w);

  unsigned int xpA[16], xpB[16];
  float v[16];
  #pragma unroll
  for (int l = 0; l < 16; ++l) {
    const float4 xv = *reinterpret_cast<const float4*>(layers + (size_t)l * MTOK * DDIM + base);
    v[l] = q0 * xv.x + q1 * xv.y + q2 * xv.z + q3 * xv.w;
    xpA[l] = ((unsigned int)(unsigned short)f2b(xv.y) << 16) | (unsigned short)f2b(xv.x);
    xpB[l] = ((unsigned int)(unsigned short)f2b(xv.w) << 16) | (unsigned short)f2b(xv.z);
  }

  #pragma unroll
  for (int j = 0; j < 8; ++j) {
    const bool hi = (lane & 1);
    float send = hi ? v[j] : v[j + 8];
    float keep = hi ? v[j + 8] : v[j];
    v[j] = keep + __shfl_xor(send, 1, 64);
  }
  #pragma unroll
  for (int j = 0; j < 4; ++j) {
    const bool hi = (lane & 2);
    float send = hi ? v[j] : v[j + 4];
    float keep = hi ? v[j + 4] : v[j];
    v[j] = keep + __shfl_xor(send, 2, 64);
  }
  #pragma unroll
  for (int j = 0; j < 2; ++j) {
    const bool hi = (lane & 4);
    float send = hi ? v[j] : v[j + 2];
    float keep = hi ? v[j + 2] : v[j];
    v[j] = keep + __shfl_xor(send, 4, 64);
  }
  {
    const bool hi = (lane & 8);
    float send = hi ? v[0] : v[1];
    float keep = hi ? v[1] : v[0];
    v[0] = keep + __shfl_xor(send, 8, 64);
  }
  v[0] += __shfl_xor(v[0], 16, 64);
  v[0] += __shfl_xor(v[0], 32, 64);
  if (lane < 16) {
    int l = ((lane & 1) << 3) | ((lane & 2) << 1) | ((lane & 4) >> 1) | ((lane & 8) >> 3);
    s_red[wave][l] = v[0];
  }
  __syncthreads();
  if (tid < 16)
    s_scores[tid] = s_red[0][tid] + s_red[1][tid] + s_red[2][tid] + s_red[3][tid];
  __syncthreads();

  const float inv = 1.0f / (32.0f * fabsf(temp[0]));
  float sc[16];
  float mx = -1e30f;
  #pragma unroll
  for (int l = 0; l < 16; ++l) { sc[l] = s_scores[l] * inv; mx = fmaxf(mx, sc[l]); }
  float se = 0.f;
  #pragma unroll
  for (int l = 0; l < 16; ++l) { sc[l] = __expf(sc[l] - mx); se += sc[l]; }
  const float rse = 1.0f / se;
  float t2 = 0.f;
  #pragma unroll
  for (int l = 0; l < 16; ++l) { sc[l] = sc[l] * rse * s_scales[l]; t2 += sc[l]; }
  const float rden = 1.0f / (t2 + 1e-6f);
  #pragma unroll
  for (int l = 0; l < 16; ++l) sc[l] *= s_scales[l] * rden;

  float o0 = 0.f, o1 = 0.f, o2 = 0.f, o3 = 0.f;
  #pragma unroll
  for (int l = 0; l < 16; ++l) {
    const float c = sc[l];
    o0 += c * bitsf(xpA[l] << 16);
    o1 += c * bitsf(xpA[l] & 0xffff0000u);
    o2 += c * bitsf(xpB[l] << 16);
    o3 += c * bitsf(xpB[l] & 0xffff0000u);
  }

  float sm = o0 + o1 + o2 + o3;
  float sq = o0 * o0 + o1 * o1 + o2 * o2 + o3 * o3;
  #pragma unroll
  for (int off = 1; off < 64; off <<= 1) {
    sm += __shfl_xor(sm, off, 64);
    sq += __shfl_xor(sq, off, 64);
  }
  if (lane == 0) { s_mv[wave][0] = sm; s_mv[wave][1] = sq; }
  __syncthreads();
  const float tsm = s_mv[0][0] + s_mv[1][0] + s_mv[2][0] + s_mv[3][0];
  const float tsq = s_mv[0][1] + s_mv[1][1] + s_mv[2][1] + s_mv[3][1];
  const float mean = tsm * (1.0f / 1024.0f);
  const float varv = tsq * (1.0f / 1024.0f) - mean * mean;
  const float rstd = rsqrtf(varv + 1e-5f);

  const float4 lw = *reinterpret_cast<const float4*>(lnw + (size_t)tid * 4);
  const float4 lb = *reinterpret_cast<const float4*>(lnb + (size_t)tid * 4);
  float4 res;
  res.x = (o0 - mean) * rstd * lw.x + lb.x;
  res.y = (o1 - mean) * rstd * lw.y + lb.y;
  res.z = (o2 - mean) * rstd * lw.z + lb.z;
  res.w = (o3 - mean) * rstd * lw.w + lb.w;
  *reinterpret_cast<float4*>(out + base) = res;
}

extern "C" void kernel_launch(void* const* d_in, const int* in_sizes, int n_in,
                              void* d_out, int out_size, void* d_ws, size_t ws_size,
                              hipStream_t stream)
{
  const float* layers = (const float*)d_in[0];   // [16][2][2048][1024]
  const float* wq     = (const float*)d_in[1];   // [1024][1024]
  const float* wk     = (const float*)d_in[2];   // [1024][1024]
  const float* scales = (const float*)d_in[3];   // [16]
  const float* temp   = (const float*)d_in[4];   // [1]
  const float* lnw    = (const float*)d_in[5];   // [1024]
  const float* lnb    = (const float*)d_in[6];   // [1024]
  float* out = (float*)d_out;

  short* xb_ws  = (short*)d_ws;                          // [4096][1024] bf16
  short* wt_ws  = xb_ws + (size_t)MTOK * DDIM;           // [1024][1024] bf16
  short* qk_ws  = wt_ws + (size_t)DDIM * DDIM;           // [4096][1024] bf16
  float* dummy  = (float*)(qk_ws + (size_t)MTOK * DDIM); // [4096][1024] f32 scratch

  const float* xlast = layers + (size_t)(LNUM - 1) * MTOK * DDIM;

  pre_k<<<dim3(256 + MTOK * DDIM / 2048), dim3(256), 0, stream>>>(wk, wq, wt_ws, xlast, xb_ws);
  qk_gemm_k<<<dim3(64, 16), dim3(256), 0, stream>>>(xb_ws, wt_ws, qk_ws);
  // Timing probe: duplicate fused into scratch, then the real one.
  fused_k<<<dim3(MTOK), dim3(256), 0, stream>>>(layers, qk_ws, scales, temp, lnw, lnb, dummy);
  fused_k<<<dim3(MTOK), dim3(256), 0, stream>>>(layers, qk_ws, scales, temp, lnw, lnb, out);
}

// Round 9
// 92.541 us; speedup vs baseline: 1.5455x; 1.5455x over previous
//
#include <hip/hip_runtime.h>
#include <hip/hip_bf16.h>

#define LNUM 16
#define DDIM 1024
#define MTOK 4096   // B*T = 2*2048

using bf16x8 = __attribute__((ext_vector_type(8))) short;
using s4v    = __attribute__((ext_vector_type(4))) short;
using f32x4  = __attribute__((ext_vector_type(4))) float;

__device__ inline short f2b(float f) {
  __hip_bfloat16 h = __float2bfloat16(f);
  union { __hip_bfloat16 h; short s; } u; u.h = h; return u.s;
}
__device__ inline float b2f(short s) {
  unsigned int u = ((unsigned int)(unsigned short)s) << 16;
  float f; __builtin_memcpy(&f, &u, 4); return f;
}
__device__ inline float bitsf(unsigned int u) {
  float f; __builtin_memcpy(&f, &u, 4); return f;
}

// ---------------------------------------------------------------------------
// Merged prologue kernel (R6-identical).
// ---------------------------------------------------------------------------
__global__ __launch_bounds__(256)
void pre_k(const float* __restrict__ wk, const float* __restrict__ wq,
           short* __restrict__ Wt,
           const float* __restrict__ xlast, short* __restrict__ xb)
{
  __shared__ short As[2][64 * 64];
  __shared__ short Bs[2][64 * 64];
  const int tid = threadIdx.x;

  if (blockIdx.x >= 256) {
    const size_t i = ((size_t)(blockIdx.x - 256) * 256 + tid) * 8;
    const float4 a = *reinterpret_cast<const float4*>(xlast + i);
    const float4 b = *reinterpret_cast<const float4*>(xlast + i + 4);
    bf16x8 v = { f2b(a.x), f2b(a.y), f2b(a.z), f2b(a.w),
                 f2b(b.x), f2b(b.y), f2b(b.z), f2b(b.w) };
    *reinterpret_cast<bf16x8*>(xb + i) = v;
    return;
  }

  const int lane = tid & 63;
  const int wave = tid >> 6;
  const int m0 = (blockIdx.x & 15) * 64;
  const int n0 = (blockIdx.x >> 4) * 64;
  const int wm = (wave >> 1) * 32;
  const int wn = (wave & 1) * 32;

  f32x4 acc[2][2] = {};
  const int col = tid & 63;
  const int kg  = tid >> 6;

  float ar[16], br[16];
  auto load = [&](int k0) {
    #pragma unroll
    for (int j = 0; j < 16; ++j) {
      const size_t k = (size_t)(k0 + kg * 16 + j);
      ar[j] = wk[k * 1024 + m0 + col];
      br[j] = wq[k * 1024 + n0 + col];
    }
  };
  auto store_lds = [&](int buf) {
    bf16x8 va0 = { f2b(ar[0]), f2b(ar[1]), f2b(ar[2]), f2b(ar[3]),
                   f2b(ar[4]), f2b(ar[5]), f2b(ar[6]), f2b(ar[7]) };
    bf16x8 va1 = { f2b(ar[8]), f2b(ar[9]), f2b(ar[10]), f2b(ar[11]),
                   f2b(ar[12]), f2b(ar[13]), f2b(ar[14]), f2b(ar[15]) };
    bf16x8 vb0 = { f2b(br[0]), f2b(br[1]), f2b(br[2]), f2b(br[3]),
                   f2b(br[4]), f2b(br[5]), f2b(br[6]), f2b(br[7]) };
    bf16x8 vb1 = { f2b(br[8]), f2b(br[9]), f2b(br[10]), f2b(br[11]),
                   f2b(br[12]), f2b(br[13]), f2b(br[14]), f2b(br[15]) };
    const int sw = (col & 7) << 4;
    const int b0 = (col * 128 + kg * 32) ^ sw;
    const int b1 = (col * 128 + kg * 32 + 16) ^ sw;
    char* pa = (char*)&As[buf][0];
    char* pb = (char*)&Bs[buf][0];
    *reinterpret_cast<bf16x8*>(pa + b0) = va0;
    *reinterpret_cast<bf16x8*>(pa + b1) = va1;
    *reinterpret_cast<bf16x8*>(pb + b0) = vb0;
    *reinterpret_cast<bf16x8*>(pb + b1) = vb1;
  };

  const int rl = lane & 15;
  const int hi = lane >> 4;
  auto compute = [&](int buf) {
    #pragma unroll
    for (int kk = 0; kk < 2; ++kk) {
      bf16x8 af[2], bfv[2];
      #pragma unroll
      for (int f = 0; f < 2; ++f) {
        const int row = wm + f * 16 + rl;
        af[f] = *reinterpret_cast<const bf16x8*>(
            (const char*)&As[buf][0] + ((row * 128 + kk * 64 + hi * 16) ^ ((row & 7) << 4)));
      }
      #pragma unroll
      for (int g = 0; g < 2; ++g) {
        const int row = wn + g * 16 + rl;
        bfv[g] = *reinterpret_cast<const bf16x8*>(
            (const char*)&Bs[buf][0] + ((row * 128 + kk * 64 + hi * 16) ^ ((row & 7) << 4)));
      }
      #pragma unroll
      for (int f = 0; f < 2; ++f)
        #pragma unroll
        for (int g = 0; g < 2; ++g)
          acc[f][g] = __builtin_amdgcn_mfma_f32_16x16x32_bf16(af[f], bfv[g], acc[f][g], 0, 0, 0);
    }
  };

  load(0);
  for (int t = 0; t < 16; ++t) {
    store_lds(t & 1);
    if (t < 15) load((t + 1) * 64);
    __syncthreads();
    compute(t & 1);
  }

  const int cl = lane & 15;
  const int rb = (lane >> 4) * 4;
  #pragma unroll
  for (int f = 0; f < 2; ++f)
    #pragma unroll
    for (int g = 0; g < 2; ++g) {
      size_t c = (size_t)(n0 + wn + g * 16 + cl);
      #pragma unroll
      for (int r = 0; r < 4; ++r) {
        size_t rr = (size_t)(m0 + wm + f * 16 + rb + r);
        Wt[rr * 1024 + c] = f2b(acc[f][g][r]);
      }
    }
}

// ---------------------------------------------------------------------------
// qk = xb @ Wt^T : A bf16 [4096][1024], B=Wt bf16 [1024][1024] ([n][k]).
// 128x128 tile, 8 waves (512 thr), grid 32x8 = 256 blocks. BK=64, LDS 64 KB.
// Same proven staging (glds w=16, pre-swizzled src + swizzled ds_read) and
// __syncthreads 2-phase dbuf; 16 MFMA/wave/K-step (2x R6's per-barrier work),
// half the cache traffic (A re-read x8 instead of x16).
// ---------------------------------------------------------------------------
__global__ __launch_bounds__(512)
void qk_gemm_k(const short* __restrict__ A, const short* __restrict__ B,
               short* __restrict__ C)
{
  __shared__ short As[2][128 * 64];
  __shared__ short Bs[2][128 * 64];
  const int tid  = threadIdx.x;
  const int lane = tid & 63;
  const int wave = tid >> 6;          // 0..7
  const int m0 = blockIdx.x * 128;
  const int n0 = blockIdx.y * 128;
  const int wm = (wave >> 2) * 64;    // 2 wave-rows
  const int wn = (wave & 3) * 32;     // 4 wave-cols

  f32x4 acc[4][2] = {};

  const int srow = lane >> 3;
  const int swz  = ((lane & 7) * 16) ^ (srow << 4);

  auto stage = [&](int buf, int k0) {
    #pragma unroll
    for (int c = 0; c < 2; ++c) {
      const int ch = wave * 2 + c;    // 16 chunks of 8 rows (A: 128 rows)
      const int r  = ch * 8 + srow;
      const short* ga = A + (size_t)(m0 + r) * 1024 + k0 + (swz >> 1);
      __builtin_amdgcn_global_load_lds(
          (const __attribute__((address_space(1))) void*)ga,
          (__attribute__((address_space(3))) void*)&As[buf][ch * 512], 16, 0, 0);
      const short* gb = B + (size_t)(n0 + r) * 1024 + k0 + (swz >> 1);
      __builtin_amdgcn_global_load_lds(
          (const __attribute__((address_space(1))) void*)gb,
          (__attribute__((address_space(3))) void*)&Bs[buf][ch * 512], 16, 0, 0);
    }
  };

  const int rl = lane & 15;
  const int hi = lane >> 4;
  auto compute = [&](int buf) {
    #pragma unroll
    for (int kk = 0; kk < 2; ++kk) {
      bf16x8 af[4], bfv[2];
      #pragma unroll
      for (int i = 0; i < 4; ++i) {
        const int row = wm + i * 16 + rl;
        af[i] = *reinterpret_cast<const bf16x8*>(
            (const char*)&As[buf][0] + ((row * 128 + kk * 64 + hi * 16) ^ ((row & 7) << 4)));
      }
      #pragma unroll
      for (int g = 0; g < 2; ++g) {
        const int row = wn + g * 16 + rl;
        bfv[g] = *reinterpret_cast<const bf16x8*>(
            (const char*)&Bs[buf][0] + ((row * 128 + kk * 64 + hi * 16) ^ ((row & 7) << 4)));
      }
      #pragma unroll
      for (int i = 0; i < 4; ++i)
        #pragma unroll
        for (int g = 0; g < 2; ++g)
          acc[i][g] = __builtin_amdgcn_mfma_f32_16x16x32_bf16(af[i], bfv[g], acc[i][g], 0, 0, 0);
    }
  };

  stage(0, 0);
  __syncthreads();
  int buf = 0;
  for (int t = 0; t < 16; ++t) {
    if (t < 15) stage(buf ^ 1, (t + 1) * 64);
    compute(buf);
    __syncthreads();
    buf ^= 1;
  }

  const int cl = lane & 15;
  const int rb = (lane >> 4) * 4;
  #pragma unroll
  for (int i = 0; i < 4; ++i)
    #pragma unroll
    for (int g = 0; g < 2; ++g) {
      size_t c = (size_t)(n0 + wn + g * 16 + cl);
      #pragma unroll
      for (int r = 0; r < 4; ++r) {
        size_t rr = (size_t)(m0 + wm + i * 16 + rb + r);
        C[rr * 1024 + c] = f2b(acc[i][g][r]);
      }
    }
}

// ---------------------------------------------------------------------------
// Fused pass (R6-identical, single launch).
// ---------------------------------------------------------------------------
__global__ __launch_bounds__(256)
void fused_k(const float* __restrict__ layers, const short* __restrict__ qk,
             const float* __restrict__ scales, const float* __restrict__ temp,
             const float* __restrict__ lnw, const float* __restrict__ lnb,
             float* __restrict__ out)
{
  const int p    = blockIdx.x;
  const int tid  = threadIdx.x;
  const int lane = tid & 63;
  const int wave = tid >> 6;

  __shared__ float s_scales[16];
  __shared__ float s_red[4][16];
  __shared__ float s_scores[16];
  __shared__ float s_mv[4][2];

  if (tid < 16) s_scales[tid] = scales[tid];

  const size_t base = (size_t)p * DDIM + (size_t)tid * 4;
  s4v qv = *reinterpret_cast<const s4v*>(qk + base);
  const float q0 = b2f(qv.x), q1 = b2f(qv.y), q2 = b2f(qv.z), q3 = b2f(qv.w);

  unsigned int xpA[16], xpB[16];
  float v[16];
  #pragma unroll
  for (int l = 0; l < 16; ++l) {
    const float4 xv = *reinterpret_cast<const float4*>(layers + (size_t)l * MTOK * DDIM + base);
    v[l] = q0 * xv.x + q1 * xv.y + q2 * xv.z + q3 * xv.w;
    xpA[l] = ((unsigned int)(unsigned short)f2b(xv.y) << 16) | (unsigned short)f2b(xv.x);
    xpB[l] = ((unsigned int)(unsigned short)f2b(xv.w) << 16) | (unsigned short)f2b(xv.z);
  }

  #pragma unroll
  for (int j = 0; j < 8; ++j) {
    const bool hi = (lane & 1);
    float send = hi ? v[j] : v[j + 8];
    float keep = hi ? v[j + 8] : v[j];
    v[j] = keep + __shfl_xor(send, 1, 64);
  }
  #pragma unroll
  for (int j = 0; j < 4; ++j) {
    const bool hi = (lane & 2);
    float send = hi ? v[j] : v[j + 4];
    float keep = hi ? v[j + 4] : v[j];
    v[j] = keep + __shfl_xor(send, 2, 64);
  }
  #pragma unroll
  for (int j = 0; j < 2; ++j) {
    const bool hi = (lane & 4);
    float send = hi ? v[j] : v[j + 2];
    float keep = hi ? v[j + 2] : v[j];
    v[j] = keep + __shfl_xor(send, 4, 64);
  }
  {
    const bool hi = (lane & 8);
    float send = hi ? v[0] : v[1];
    float keep = hi ? v[1] : v[0];
    v[0] = keep + __shfl_xor(send, 8, 64);
  }
  v[0] += __shfl_xor(v[0], 16, 64);
  v[0] += __shfl_xor(v[0], 32, 64);
  if (lane < 16) {
    int l = ((lane & 1) << 3) | ((lane & 2) << 1) | ((lane & 4) >> 1) | ((lane & 8) >> 3);
    s_red[wave][l] = v[0];
  }
  __syncthreads();
  if (tid < 16)
    s_scores[tid] = s_red[0][tid] + s_red[1][tid] + s_red[2][tid] + s_red[3][tid];
  __syncthreads();

  const float inv = 1.0f / (32.0f * fabsf(temp[0]));
  float sc[16];
  float mx = -1e30f;
  #pragma unroll
  for (int l = 0; l < 16; ++l) { sc[l] = s_scores[l] * inv; mx = fmaxf(mx, sc[l]); }
  float se = 0.f;
  #pragma unroll
  for (int l = 0; l < 16; ++l) { sc[l] = __expf(sc[l] - mx); se += sc[l]; }
  const float rse = 1.0f / se;
  float t2 = 0.f;
  #pragma unroll
  for (int l = 0; l < 16; ++l) { sc[l] = sc[l] * rse * s_scales[l]; t2 += sc[l]; }
  const float rden = 1.0f / (t2 + 1e-6f);
  #pragma unroll
  for (int l = 0; l < 16; ++l) sc[l] *= s_scales[l] * rden;

  float o0 = 0.f, o1 = 0.f, o2 = 0.f, o3 = 0.f;
  #pragma unroll
  for (int l = 0; l < 16; ++l) {
    const float c = sc[l];
    o0 += c * bitsf(xpA[l] << 16);
    o1 += c * bitsf(xpA[l] & 0xffff0000u);
    o2 += c * bitsf(xpB[l] << 16);
    o3 += c * bitsf(xpB[l] & 0xffff0000u);
  }

  float sm = o0 + o1 + o2 + o3;
  float sq = o0 * o0 + o1 * o1 + o2 * o2 + o3 * o3;
  #pragma unroll
  for (int off = 1; off < 64; off <<= 1) {
    sm += __shfl_xor(sm, off, 64);
    sq += __shfl_xor(sq, off, 64);
  }
  if (lane == 0) { s_mv[wave][0] = sm; s_mv[wave][1] = sq; }
  __syncthreads();
  const float tsm = s_mv[0][0] + s_mv[1][0] + s_mv[2][0] + s_mv[3][0];
  const float tsq = s_mv[0][1] + s_mv[1][1] + s_mv[2][1] + s_mv[3][1];
  const float mean = tsm * (1.0f / 1024.0f);
  const float varv = tsq * (1.0f / 1024.0f) - mean * mean;
  const float rstd = rsqrtf(varv + 1e-5f);

  const float4 lw = *reinterpret_cast<const float4*>(lnw + (size_t)tid * 4);
  const float4 lb = *reinterpret_cast<const float4*>(lnb + (size_t)tid * 4);
  float4 res;
  res.x = (o0 - mean) * rstd * lw.x + lb.x;
  res.y = (o1 - mean) * rstd * lw.y + lb.y;
  res.z = (o2 - mean) * rstd * lw.z + lb.z;
  res.w = (o3 - mean) * rstd * lw.w + lb.w;
  *reinterpret_cast<float4*>(out + base) = res;
}

extern "C" void kernel_launch(void* const* d_in, const int* in_sizes, int n_in,
                              void* d_out, int out_size, void* d_ws, size_t ws_size,
                              hipStream_t stream)
{
  const float* layers = (const float*)d_in[0];   // [16][2][2048][1024]
  const float* wq     = (const float*)d_in[1];   // [1024][1024]
  const float* wk     = (const float*)d_in[2];   // [1024][1024]
  const float* scales = (const float*)d_in[3];   // [16]
  const float* temp   = (const float*)d_in[4];   // [1]
  const float* lnw    = (const float*)d_in[5];   // [1024]
  const float* lnb    = (const float*)d_in[6];   // [1024]
  float* out = (float*)d_out;

  short* xb_ws = (short*)d_ws;                           // [4096][1024] bf16
  short* wt_ws = xb_ws + (size_t)MTOK * DDIM;            // [1024][1024] bf16
  short* qk_ws = wt_ws + (size_t)DDIM * DDIM;            // [4096][1024] bf16

  const float* xlast = layers + (size_t)(LNUM - 1) * MTOK * DDIM;

  pre_k<<<dim3(256 + MTOK * DDIM / 2048), dim3(256), 0, stream>>>(wk, wq, wt_ws, xlast, xb_ws);
  qk_gemm_k<<<dim3(32, 8), dim3(512), 0, stream>>>(xb_ws, wt_ws, qk_ws);
  fused_k<<<dim3(MTOK), dim3(256), 0, stream>>>(layers, qk_ws, scales, temp, lnw, lnb, out);
}